// Round 1
// baseline (457.056 us; speedup 1.0000x reference)
//
#include <hip/hip_runtime.h>

#define MDIM 32768
#define NDIM 4096
#define KDIM 1024

typedef __attribute__((ext_vector_type(8))) short short8;   // 8 x bf16 bits (4 VGPR)
typedef __attribute__((ext_vector_type(4))) short shortx4;  // 8B store
typedef __attribute__((ext_vector_type(4))) float floatx4;
typedef __attribute__((ext_vector_type(2))) float floatx2;

// e4m3fn round-trip via HW converts (RNE; OCP format on gfx950).
__device__ __forceinline__ floatx2 fp8_roundtrip2(float a, float b) {
    int p = __builtin_amdgcn_cvt_pk_fp8_f32(a, b, 0, false);
    return __builtin_amdgcn_cvt_pk_f32_fp8(p, false);
}

// e4m3 values (<=3 mantissa bits, exp range [-9,8]) are EXACT in bf16: truncate.
__device__ __forceinline__ short f32_to_bf16_bits(float f) {
    return (short)(__float_as_uint(f) >> 16);
}

// ---- quantize x: f32 [M,K] -> bf16(fp8-roundtripped) [M,K] ----
__global__ __launch_bounds__(256) void quant_x_kernel(
    const float* __restrict__ x, short* __restrict__ out, int n4) {
    int idx = blockIdx.x * blockDim.x + threadIdx.x;
    int stride = gridDim.x * blockDim.x;
    const floatx4* xv = (const floatx4*)x;
    shortx4* ov = (shortx4*)out;
    for (int i = idx; i < n4; i += stride) {
        floatx4 v = xv[i];
        floatx2 q01 = fp8_roundtrip2(v.x, v.y);
        floatx2 q23 = fp8_roundtrip2(v.z, v.w);
        shortx4 o;
        o.x = f32_to_bf16_bits(q01.x);
        o.y = f32_to_bf16_bits(q01.y);
        o.z = f32_to_bf16_bits(q23.x);
        o.w = f32_to_bf16_bits(q23.y);
        ov[i] = o;
    }
}

// ---- quantize + transpose w: f32 [K,N] -> bf16 [N,K] ----
__global__ __launch_bounds__(256) void quant_w_kernel(
    const float* __restrict__ w, short* __restrict__ wT) {
    __shared__ short tile[64][66];  // +2 shorts pad = +1 bank -> conflict-free transpose
    int nbase = blockIdx.x * 64;
    int kbase = blockIdx.y * 64;
    int t = threadIdx.x;
#pragma unroll
    for (int i = 0; i < 16; ++i) {
        int idx = t + i * 256;
        int r = idx >> 6;   // k
        int c = idx & 63;   // n
        float f = w[(long)(kbase + r) * NDIM + nbase + c];
        floatx2 q = fp8_roundtrip2(f, 0.0f);
        tile[r][c] = f32_to_bf16_bits(q.x);
    }
    __syncthreads();
#pragma unroll
    for (int i = 0; i < 16; ++i) {
        int idx = t + i * 256;
        int r = idx >> 6;   // n
        int c = idx & 63;   // k
        wT[(long)(nbase + r) * KDIM + kbase + c] = tile[c][r];
    }
}

// ---- GEMM: A bf16 [M,K] (row-major), BT bf16 [N,K] (row-major), C f32 [M,N] ----
// m97-class: 128x128 tile, BK=64, 4 waves (2x2), each wave 4x4 frags of 16x16x32.
// LDS XOR-swizzle (byte ^= (row&7)<<4) applied via pre-swizzled global source
// (global_load_lds writes linearly: wave-uniform base + lane*16).
#define GLOAD_LDS16(gp, lp)                                        \
    __builtin_amdgcn_global_load_lds(                              \
        (const __attribute__((address_space(1))) void*)(gp),       \
        (__attribute__((address_space(3))) void*)(lp), 16, 0, 0)

__global__ __launch_bounds__(256) void gemm_kernel(
    const short* __restrict__ A, const short* __restrict__ BT,
    const float* __restrict__ bias, float* __restrict__ C) {
    constexpr int BM = 128, BN = 128, BK = 64;
    __shared__ short As[BM * BK];  // [row][k] row-major, 128B/row, data XOR-swizzled
    __shared__ short Bs[BN * BK];

    const int tid = threadIdx.x;
    const int lane = tid & 63;
    const int w = tid >> 6;          // wave 0..3
    const int wr = w >> 1, wc = w & 1;

    const int bm = blockIdx.y * BM;
    const int bn = blockIdx.x * BN;

    // Staging: wave w stages rows [w*32, w*32+32) of each tile, 4 loads of
    // (64 lanes x 16B) = 8 rows each. Lane l -> LDS byte base+l*16 =
    // row (l>>3), col-chunk (l&7). Source col-chunk is XOR-swizzled by row&7.
    const int srow = w * 32 + (lane >> 3);                       // + j*8
    const int scol = 8 * ((lane & 7) ^ ((lane >> 3) & 7));       // swizzled k-offset (elems)
    const long aBase = (long)(bm + srow) * KDIM + scol;
    const long bBase = (long)(bn + srow) * KDIM + scol;

    floatx4 acc[4][4] = {};

    const int lr = lane & 15;              // frag row (A) / col (B,C)
    const int lkb = (lane >> 4) * 8;       // frag k-base
    const int swz = (lr & 7) << 4;         // read-side XOR (row&7 == lr&7 here)

    for (int k0 = 0; k0 < KDIM; k0 += BK) {
#pragma unroll
        for (int j = 0; j < 4; ++j)
            GLOAD_LDS16(A + aBase + k0 + (long)j * 8 * KDIM, As + (w * 32 + j * 8) * BK);
#pragma unroll
        for (int j = 0; j < 4; ++j)
            GLOAD_LDS16(BT + bBase + k0 + (long)j * 8 * KDIM, Bs + (w * 32 + j * 8) * BK);
        __syncthreads();   // drains vmcnt -> LDS ready

#pragma unroll
        for (int kk = 0; kk < BK; kk += 32) {
            const int koff = ((kk + lkb) * 2) ^ swz;   // byte offset within row
            short8 a[4], b[4];
#pragma unroll
            for (int m = 0; m < 4; ++m) {
                int row = wr * 64 + m * 16 + lr;
                a[m] = *(const short8*)((const char*)As + row * (BK * 2) + koff);
            }
#pragma unroll
            for (int n = 0; n < 4; ++n) {
                int row = wc * 64 + n * 16 + lr;
                b[n] = *(const short8*)((const char*)Bs + row * (BK * 2) + koff);
            }
#pragma unroll
            for (int m = 0; m < 4; ++m)
#pragma unroll
                for (int n = 0; n < 4; ++n)
                    acc[m][n] = __builtin_amdgcn_mfma_f32_16x16x32_bf16(
                        a[m], b[n], acc[m][n], 0, 0, 0);
        }
        __syncthreads();   // all reads done before next stage overwrites
    }

    // Epilogue: C/D layout col=lane&15, row=(lane>>4)*4+i. + bias.
    const int l4 = (lane >> 4) << 2;
#pragma unroll
    for (int n = 0; n < 4; ++n) {
        int gcol = bn + wc * 64 + n * 16 + lr;
        float bv = bias[gcol];
#pragma unroll
        for (int m = 0; m < 4; ++m) {
            int grow = bm + wr * 64 + m * 16 + l4;
#pragma unroll
            for (int i = 0; i < 4; ++i)
                C[(long)(grow + i) * NDIM + gcol] = acc[m][n][i] + bv;
        }
    }
}

extern "C" void kernel_launch(void* const* d_in, const int* in_sizes, int n_in,
                              void* d_out, int out_size, void* d_ws, size_t ws_size,
                              hipStream_t stream) {
    (void)in_sizes; (void)n_in; (void)out_size; (void)ws_size;
    const float* x = (const float*)d_in[0];
    const float* wk = (const float*)d_in[1];
    const float* bias = (const float*)d_in[2];
    float* out = (float*)d_out;

    short* xq = (short*)d_ws;                                        // 64 MB
    short* wT = (short*)((char*)d_ws + (size_t)MDIM * KDIM * 2);     // 8 MB

    quant_x_kernel<<<2048, 256, 0, stream>>>(x, xq, MDIM * KDIM / 4);
    quant_w_kernel<<<dim3(NDIM / 64, KDIM / 64), 256, 0, stream>>>(wk, wT);
    gemm_kernel<<<dim3(NDIM / 128, MDIM / 128), 256, 0, stream>>>(xq, wT, bias, out);
}

// Round 2
// 406.909 us; speedup vs baseline: 1.1232x; 1.1232x over previous
//
#include <hip/hip_runtime.h>

#define MDIM 32768
#define NDIM 4096
#define KDIM 1024

typedef __attribute__((ext_vector_type(8))) short short8;   // 8 x bf16 bits (4 VGPR)
typedef __attribute__((ext_vector_type(4))) short shortx4;  // 8B store
typedef __attribute__((ext_vector_type(4))) float floatx4;
typedef __attribute__((ext_vector_type(2))) float floatx2;

// e4m3fn round-trip via HW converts (RNE; OCP format on gfx950).
__device__ __forceinline__ floatx2 fp8_roundtrip2(float a, float b) {
    int p = __builtin_amdgcn_cvt_pk_fp8_f32(a, b, 0, false);
    return __builtin_amdgcn_cvt_pk_f32_fp8(p, false);
}

// e4m3 values are EXACT in bf16: truncate.
__device__ __forceinline__ short f32_to_bf16_bits(float f) {
    return (short)(__float_as_uint(f) >> 16);
}

// ---- quantize x: f32 [M,K] -> bf16(fp8-roundtripped) [M,K] ----
__global__ __launch_bounds__(256) void quant_x_kernel(
    const float* __restrict__ x, short* __restrict__ out, int n4) {
    int idx = blockIdx.x * blockDim.x + threadIdx.x;
    int stride = gridDim.x * blockDim.x;
    const floatx4* xv = (const floatx4*)x;
    shortx4* ov = (shortx4*)out;
    for (int i = idx; i < n4; i += stride) {
        floatx4 v = xv[i];
        floatx2 q01 = fp8_roundtrip2(v.x, v.y);
        floatx2 q23 = fp8_roundtrip2(v.z, v.w);
        shortx4 o;
        o.x = f32_to_bf16_bits(q01.x);
        o.y = f32_to_bf16_bits(q01.y);
        o.z = f32_to_bf16_bits(q23.x);
        o.w = f32_to_bf16_bits(q23.y);
        ov[i] = o;
    }
}

// ---- quantize + transpose w: f32 [K,N] -> bf16 [N,K] ----
__global__ __launch_bounds__(256) void quant_w_kernel(
    const float* __restrict__ w, short* __restrict__ wT) {
    __shared__ short tile[64][66];
    int nbase = blockIdx.x * 64;
    int kbase = blockIdx.y * 64;
    int t = threadIdx.x;
#pragma unroll
    for (int i = 0; i < 16; ++i) {
        int idx = t + i * 256;
        int r = idx >> 6;   // k
        int c = idx & 63;   // n
        float f = w[(long)(kbase + r) * NDIM + nbase + c];
        floatx2 q = fp8_roundtrip2(f, 0.0f);
        tile[r][c] = f32_to_bf16_bits(q.x);
    }
    __syncthreads();
#pragma unroll
    for (int i = 0; i < 16; ++i) {
        int idx = t + i * 256;
        int r = idx >> 6;   // n
        int c = idx & 63;   // k
        wT[(long)(nbase + r) * KDIM + kbase + c] = tile[c][r];
    }
}

// ================= GEMM: 256x256 tile, BK=32, 4-deep LDS rotation =============
// A bf16 [M,K], BT bf16 [N,K], C f32 [M,N]. 8 waves (2 M x 4 N), 128x64/wave.
// LDS per buf per operand: [128 rows][64 shorts] = 16 KB; row r packs M-rows
// (r, r+128) as the two 32-short k-halves. XOR swizzle: 16B chunk p in row r
// holds logical chunk p^(r&7) (both-sides involution; zero bank conflicts).
// Pipeline: stage tile t+3, s_waitcnt vmcnt(12) (lands tile t), raw s_barrier,
// 12 ds_read_b128 + 32 MFMA (setprio 1), s_barrier. Never drains vmcnt to 0
// until the epilogue (12 -> 8 -> 4 -> 0).

#define GL(gp, lp)                                                 \
    __builtin_amdgcn_global_load_lds(                              \
        (const __attribute__((address_space(1))) void*)(gp),       \
        (__attribute__((address_space(3))) void*)(lp), 16, 0, 0)

#define VMCNT(n) asm volatile("s_waitcnt vmcnt(" #n ")" ::: "memory")
#define BARS()  { __builtin_amdgcn_s_barrier(); __builtin_amdgcn_sched_barrier(0); }

__global__ __launch_bounds__(512) void gemm_kernel(
    const short* __restrict__ A, const short* __restrict__ BT,
    const float* __restrict__ bias, float* __restrict__ C) {
    __shared__ char lds[131072];   // A: bufs 0..3 at b*16384; B: 65536 + b*16384

    const int T = threadIdx.x;
    const int lane = T & 63;
    const int w = T >> 6;            // wave 0..7
    const int wr = w >> 2;           // 0..1  (M)
    const int wc = w & 3;            // 0..3  (N)

    // XCD-aware bijective swizzle (2048 blocks, 2048%8==0), bn-major chunks.
    const int sw = (blockIdx.x & 7) * 256 + (blockIdx.x >> 3);
    const int bn = (sw >> 7) * 256;      // 16 N-blocks
    const int bm = (sw & 127) * 256;     // 128 M-blocks

    // ---- staging addresses (per-thread) ----
    const int cs = (T & 7) ^ ((T >> 3) & 7);        // logical chunk for this slot
    const int srow = ((cs >> 2) << 7) + (T >> 3);   // + j*64 per slab
    const int scol = (cs & 3) * 8;
    const long aOff = (long)(bm + srow) * KDIM + scol;
    const long bOff = (long)(bn + srow) * KDIM + scol;
    const int dstB = (T >> 3) * 128 + (T & 7) * 16; // LDS byte offset (slab 0)

#define STAGE(b_, t_) {                                                   \
        char* la_ = lds + (b_) * 16384 + dstB;                            \
        char* lb_ = lds + 65536 + (b_) * 16384 + dstB;                    \
        const short* ga_ = A + aOff + (t_) * 32;                          \
        const short* gb_ = BT + bOff + (t_) * 32;                         \
        GL(ga_, la_);            GL(ga_ + 64 * KDIM, la_ + 8192);         \
        GL(gb_, lb_);            GL(gb_ + 64 * KDIM, lb_ + 8192);         \
    }

    // ---- read-side addresses ----
    const int lr = lane & 15;
    const int swz = (lr & 7) << 4;
    const int koffA = wr * 64 + ((lane >> 4) << 4);          // logical byte col
    const int koffB = (wc >> 1) * 64 + ((lane >> 4) << 4);
    const char* ABase = lds + lr * 128 + (koffA ^ swz);
    const char* BBase = lds + 65536 + ((wc & 1) * 64 + lr) * 128 + (koffB ^ swz);

    floatx4 acc[8][4] = {};

#define COMPUTE(b_) {                                                     \
        const char* ap_ = ABase + (b_) * 16384;                           \
        const char* bp_ = BBase + (b_) * 16384;                           \
        short8 b0_ = *(const short8*)(bp_);                               \
        short8 b1_ = *(const short8*)(bp_ + 2048);                        \
        short8 b2_ = *(const short8*)(bp_ + 4096);                        \
        short8 b3_ = *(const short8*)(bp_ + 6144);                        \
        __builtin_amdgcn_s_setprio(1);                                    \
        _Pragma("unroll")                                                 \
        for (int m_ = 0; m_ < 8; ++m_) {                                  \
            short8 a_ = *(const short8*)(ap_ + m_ * 2048);                \
            acc[m_][0] = __builtin_amdgcn_mfma_f32_16x16x32_bf16(a_, b0_, acc[m_][0], 0, 0, 0); \
            acc[m_][1] = __builtin_amdgcn_mfma_f32_16x16x32_bf16(a_, b1_, acc[m_][1], 0, 0, 0); \
            acc[m_][2] = __builtin_amdgcn_mfma_f32_16x16x32_bf16(a_, b2_, acc[m_][2], 0, 0, 0); \
            acc[m_][3] = __builtin_amdgcn_mfma_f32_16x16x32_bf16(a_, b3_, acc[m_][3], 0, 0, 0); \
        }                                                                 \
        __builtin_amdgcn_s_setprio(0);                                    \
    }

    // ---- prologue: fill 3 buffers (12 loads in flight) ----
    STAGE(0, 0); STAGE(1, 1); STAGE(2, 2);

    // ---- main loop: 28 tiles, unrolled x4 (static buffer indices) ----
    for (int t = 0; t < 28; t += 4) {
        STAGE(3, t + 3); VMCNT(12); BARS(); COMPUTE(0); BARS();
        STAGE(0, t + 4); VMCNT(12); BARS(); COMPUTE(1); BARS();
        STAGE(1, t + 5); VMCNT(12); BARS(); COMPUTE(2); BARS();
        STAGE(2, t + 6); VMCNT(12); BARS(); COMPUTE(3); BARS();
    }
    // ---- epilogue tiles 28..31: drain 12 -> 8 -> 4 -> 0 ----
    STAGE(3, 31); VMCNT(12); BARS(); COMPUTE(0); BARS();
    VMCNT(8);  BARS(); COMPUTE(1); BARS();
    VMCNT(4);  BARS(); COMPUTE(2); BARS();
    VMCNT(0);  BARS(); COMPUTE(3);

    // ---- C write + bias. C/D frag: col=lane&15, row=(lane>>4)*4+i ----
    const int l4 = (lane >> 4) << 2;
#pragma unroll
    for (int n = 0; n < 4; ++n) {
        int gcol = bn + wc * 64 + n * 16 + lr;
        float bv = bias[gcol];
#pragma unroll
        for (int m = 0; m < 8; ++m) {
            long grow = bm + wr * 128 + m * 16 + l4;
#pragma unroll
            for (int i = 0; i < 4; ++i)
                C[(grow + i) * NDIM + gcol] = acc[m][n][i] + bv;
        }
    }
#undef STAGE
#undef COMPUTE
}

extern "C" void kernel_launch(void* const* d_in, const int* in_sizes, int n_in,
                              void* d_out, int out_size, void* d_ws, size_t ws_size,
                              hipStream_t stream) {
    (void)in_sizes; (void)n_in; (void)out_size; (void)ws_size;
    const float* x = (const float*)d_in[0];
    const float* wk = (const float*)d_in[1];
    const float* bias = (const float*)d_in[2];
    float* out = (float*)d_out;

    short* xq = (short*)d_ws;                                        // 64 MB
    short* wT = (short*)((char*)d_ws + (size_t)MDIM * KDIM * 2);     // 8 MB

    quant_x_kernel<<<2048, 256, 0, stream>>>(x, xq, MDIM * KDIM / 4);
    quant_w_kernel<<<dim3(NDIM / 64, KDIM / 64), 256, 0, stream>>>(wk, wT);
    gemm_kernel<<<2048, 512, 0, stream>>>(xq, wT, bias, out);
}

// Round 3
// 245.514 us; speedup vs baseline: 1.8616x; 1.6574x over previous
//
#include <hip/hip_runtime.h>

#define MDIM 32768
#define NDIM 4096
#define KDIM 1024

typedef __attribute__((ext_vector_type(4))) float floatx4;
typedef __attribute__((ext_vector_type(16))) float float16v;
typedef __attribute__((ext_vector_type(4))) int int4v;
typedef __attribute__((ext_vector_type(8))) int int8v;

// ---- quantize x: f32 [M,K] -> fp8 e4m3 bytes [M,K] (RNE, saturating) ----
__global__ __launch_bounds__(256) void quant_x_kernel(
    const float* __restrict__ x, char* __restrict__ out, int n16) {
    int idx = blockIdx.x * blockDim.x + threadIdx.x;
    int stride = gridDim.x * blockDim.x;
    const floatx4* xv = (const floatx4*)x;
    int4v* ov = (int4v*)out;
    for (int i = idx; i < n16; i += stride) {
        int4v o;
#pragma unroll
        for (int j = 0; j < 4; ++j) {
            floatx4 v = xv[i * 4 + j];
            int pk = __builtin_amdgcn_cvt_pk_fp8_f32(v.x, v.y, 0, false);
            pk = __builtin_amdgcn_cvt_pk_fp8_f32(v.z, v.w, pk, true);
            o[j] = pk;
        }
        ov[i] = o;
    }
}

// ---- quantize + transpose w: f32 [K,N] -> fp8 e4m3 [N,K] ----
__global__ __launch_bounds__(256) void quant_w_kernel(
    const float* __restrict__ w, char* __restrict__ wT) {
    __shared__ char tile[64][68];
    int nbase = blockIdx.x * 64;
    int kbase = blockIdx.y * 64;
    int t = threadIdx.x;
#pragma unroll
    for (int i = 0; i < 4; ++i) {
        int fidx = t + i * 256;      // 1024 float4s per 64x64 tile
        int r = fidx >> 4;           // k row 0..63
        int c4 = fidx & 15;          // float4 col
        floatx4 v = *(const floatx4*)&w[(long)(kbase + r) * NDIM + nbase + c4 * 4];
        int pk = __builtin_amdgcn_cvt_pk_fp8_f32(v.x, v.y, 0, false);
        pk = __builtin_amdgcn_cvt_pk_fp8_f32(v.z, v.w, pk, true);
        *(int*)&tile[r][c4 * 4] = pk;
    }
    __syncthreads();
    int n = t >> 2, kq = (t & 3) * 16;
    int outw[4];
#pragma unroll
    for (int g = 0; g < 4; ++g) {
        int v = 0;
#pragma unroll
        for (int j = 0; j < 4; ++j)
            v |= ((int)(unsigned char)tile[kq + g * 4 + j][n]) << (8 * j);
        outw[g] = v;
    }
    *(int4v*)&wT[(long)(nbase + n) * KDIM + kbase + kq] = *(int4v*)outw;
}

// ======== GEMM: MX-fp8 (unit scales). A fp8 [M,K], BT fp8 [N,K], C f32 [M,N].
// 256x256 tile, BK=128 bytes, 8 waves (2M x 4N), wave tile 128x64 = 4m x 2n
// frags of 32x32. mfma_scale_f32_32x32x64_f8f6f4, scale byte 0x7F = 2^0 (exact).
// LDS: per buf A 256x128B = 32 KB (+B 32 KB); 2 bufs = 128 KB. Rows are 128 B
// = 8 chunks of 16 B, XOR swizzle chunk ^= row&7 (both-sides involution, the
// round-1/2-verified zero-conflict geometry). Counted vmcnt(8): one tile
// (8 gloads) stays in flight; never drained to 0 until the last tile.

#define GL(gp, lp)                                                 \
    __builtin_amdgcn_global_load_lds(                              \
        (const __attribute__((address_space(1))) void*)(gp),       \
        (__attribute__((address_space(3))) void*)(lp), 16, 0, 0)

#define VMCNT(n) asm volatile("s_waitcnt vmcnt(" #n ")" ::: "memory")
#define BARS()  { __builtin_amdgcn_s_barrier(); __builtin_amdgcn_sched_barrier(0); }

#define MFMA_SC(a_, b_, c_)                                               \
    __builtin_amdgcn_mfma_scale_f32_32x32x64_f8f6f4(                      \
        (a_), (b_), (c_), 0, 0, 0, 0x7F7F7F7F, 0, 0x7F7F7F7F)

__global__ __launch_bounds__(512) void gemm_kernel(
    const char* __restrict__ A, const char* __restrict__ BT,
    const float* __restrict__ bias, float* __restrict__ C) {
    __shared__ char lds[131072];   // A: d*32768; B: 65536 + d*32768

    const int T = threadIdx.x;
    const int lane = T & 63;
    const int w = T >> 6;            // wave 0..7
    const int wr = w >> 2;           // 0..1 (M)
    const int wc = w & 3;            // 0..3 (N)

    // XCD-aware bijective swizzle (2048 blocks % 8 == 0), bn-major chunks.
    const int sw = (blockIdx.x & 7) * 256 + (blockIdx.x >> 3);
    const int bn = (sw >> 7) * 256;      // 16 N-blocks
    const int bm = (sw & 127) * 256;     // 128 M-blocks

    // ---- staging (per-thread): 512 thr x 16B covers 64 rows; 4 loads/operand.
    // LDS phys chunk (T&7) of row (T>>3)+j*64 <- logical chunk (T&7)^((T>>3)&7).
    const int cs = (T & 7) ^ ((T >> 3) & 7);
    const long aOff = (long)(bm + (T >> 3)) * KDIM + cs * 16;
    const long bOff = (long)(bn + (T >> 3)) * KDIM + cs * 16;
    const int dstB = (T >> 3) * 128 + (T & 7) * 16;

#define STAGE(d_, t_) {                                                       \
        char* la_ = lds + (d_) * 32768 + dstB;                                \
        char* lb_ = lds + 65536 + (d_) * 32768 + dstB;                        \
        const char* ga_ = A + aOff + (t_) * 128;                              \
        const char* gb_ = BT + bOff + (t_) * 128;                             \
        GL(ga_, la_);                 GL(ga_ + 64 * KDIM, la_ + 8192);        \
        GL(ga_ + 128 * KDIM, la_ + 16384); GL(ga_ + 192 * KDIM, la_ + 24576); \
        GL(gb_, lb_);                 GL(gb_ + 64 * KDIM, lb_ + 8192);        \
        GL(gb_ + 128 * KDIM, lb_ + 16384); GL(gb_ + 192 * KDIM, lb_ + 24576); \
    }

    // ---- read-side addresses ----
    const int l31 = lane & 31;
    const int kh = lane >> 5;                 // k half-wave
    const int swz = (lane & 7) << 4;          // row&7 == lane&7 for all frags
    const char* Abase = lds + (wr * 128 + l31) * 128;
    const char* Bbase = lds + 65536 + (wc * 64 + l31) * 128;

    float16v acc[4][2] = {};

    // 32B fragment load: logical byte cols col0, col0+16 (XOR-swizzled chunks).
#define LD32(dst_, base_, col0_) {                                        \
        int4v lo_ = *(const int4v*)((base_) + (((col0_) + 0) ^ swz));     \
        int4v hi_ = *(const int4v*)((base_) + (((col0_) + 16) ^ swz));    \
        dst_[0] = lo_[0]; dst_[1] = lo_[1]; dst_[2] = lo_[2]; dst_[3] = lo_[3]; \
        dst_[4] = hi_[0]; dst_[5] = hi_[1]; dst_[6] = hi_[2]; dst_[7] = hi_[3]; \
    }

#define COMPUTE(d_) {                                                     \
        const char* ap_ = Abase + (d_) * 32768;                           \
        const char* bp_ = Bbase + (d_) * 32768;                           \
        _Pragma("unroll")                                                 \
        for (int kk = 0; kk < 2; ++kk) {                                  \
            const int col0 = kk * 64 + kh * 32;                           \
            int8v b0, b1, a0, a1, a2, a3;                                 \
            LD32(b0, bp_, col0); LD32(b1, bp_ + 32 * 128, col0);          \
            LD32(a0, ap_, col0);          LD32(a1, ap_ + 4096, col0);     \
            LD32(a2, ap_ + 8192, col0);   LD32(a3, ap_ + 12288, col0);    \
            __builtin_amdgcn_s_setprio(1);                                \
            acc[0][0] = MFMA_SC(a0, b0, acc[0][0]);                       \
            acc[0][1] = MFMA_SC(a0, b1, acc[0][1]);                       \
            acc[1][0] = MFMA_SC(a1, b0, acc[1][0]);                       \
            acc[1][1] = MFMA_SC(a1, b1, acc[1][1]);                       \
            acc[2][0] = MFMA_SC(a2, b0, acc[2][0]);                       \
            acc[2][1] = MFMA_SC(a2, b1, acc[2][1]);                       \
            acc[3][0] = MFMA_SC(a3, b0, acc[3][0]);                       \
            acc[3][1] = MFMA_SC(a3, b1, acc[3][1]);                       \
            __builtin_amdgcn_s_setprio(0);                                \
        }                                                                 \
    }

    // ---- pipeline: 8 K-tiles, 2 bufs, fully unrolled, vmcnt never 0 mid-loop.
    STAGE(0, 0);
    STAGE(1, 1); VMCNT(8); BARS(); COMPUTE(0); BARS();
    STAGE(0, 2); VMCNT(8); BARS(); COMPUTE(1); BARS();
    STAGE(1, 3); VMCNT(8); BARS(); COMPUTE(0); BARS();
    STAGE(0, 4); VMCNT(8); BARS(); COMPUTE(1); BARS();
    STAGE(1, 5); VMCNT(8); BARS(); COMPUTE(0); BARS();
    STAGE(0, 6); VMCNT(8); BARS(); COMPUTE(1); BARS();
    STAGE(1, 7); VMCNT(8); BARS(); COMPUTE(0); BARS();
    VMCNT(0);  BARS(); COMPUTE(1);

    // ---- C write + bias. 32x32 C/D frag: col=lane&31, row=(reg&3)+8*(reg>>2)+4*kh.
#pragma unroll
    for (int n = 0; n < 2; ++n) {
        int gcol = bn + wc * 64 + n * 32 + l31;
        float bv = bias[gcol];
#pragma unroll
        for (int m = 0; m < 4; ++m) {
            long rbase = bm + wr * 128 + m * 32 + 4 * kh;
#pragma unroll
            for (int r = 0; r < 16; ++r) {
                long grow = rbase + (r & 3) + 8 * (r >> 2);
                C[grow * NDIM + gcol] = acc[m][n][r] + bv;
            }
        }
    }
#undef STAGE
#undef COMPUTE
#undef LD32
}

extern "C" void kernel_launch(void* const* d_in, const int* in_sizes, int n_in,
                              void* d_out, int out_size, void* d_ws, size_t ws_size,
                              hipStream_t stream) {
    (void)in_sizes; (void)n_in; (void)out_size; (void)ws_size;
    const float* x = (const float*)d_in[0];
    const float* wk = (const float*)d_in[1];
    const float* bias = (const float*)d_in[2];
    float* out = (float*)d_out;

    char* xq = (char*)d_ws;                                       // 32 MB
    char* wT = (char*)d_ws + (size_t)MDIM * KDIM;                 // 4 MB

    quant_x_kernel<<<2048, 256, 0, stream>>>(x, xq, MDIM * KDIM / 16);
    quant_w_kernel<<<dim3(NDIM / 64, KDIM / 64), 256, 0, stream>>>(wk, wT);
    gemm_kernel<<<2048, 512, 0, stream>>>(xq, wT, bias, out);
}